// Round 7
// baseline (129.440 us; speedup 1.0000x reference)
//
#include <hip/hip_runtime.h>
#include <math.h>

// Fused single-kernel DSVF biquad IIR (scipy lfilter DF2T), B=512, T=32768.
// One block per row: 512 threads (8 waves), chunk = 64 samples per thread.
// R7 = R6 (verified clean: FETCH 66/WRITE 66 MB, no spill) + software
// pipelining of the wave-synchronous transpose rounds:
//   - round j+1's 4 global quads are loaded into registers BEFORE round j's
//     asm waits, so the compiler emits counted vmcnt(4) and the next loads
//     stay in flight under round j's LDS+IIR work (R6 serialized rounds via
//     "memory"-clobber waits -> full load latency exposed every round).
//   - pass2's round-0 loads are issued BEFORE the scan; the scan's barrier
//     chain (~2 us) hides their L3/HBM latency completely.
// Per-thread live state stays ~24 scalars + 8 float4 (no spillable big
// array; R3-R5 lesson). 57 KB LDS caps occupancy at 2 blocks/CU -> backend
// budgets 128 VGPRs (4 waves/EU target); 2 blocks/CU x 256 CU = all 512
// blocks resident.
// Geometry (verified R4-R6): wave segment = 4096 samples = 16 slices of 64
// quads; round j stages slices 4j..4j+3 into the 4 KB wave buffer; lane l's
// chunk = slice l>>2, quads 16*(l&3)+k; active round = l>>4. XOR swizzle
// q^((q>>4)&7) keeps LDS banks <=2-way.
// Scan: f64 LDS Kogge-Stone over 512 chunks, P = M^64 (verified).
// HBM: x once (pass2 re-read is L3-resident), y once.

namespace {
constexpr int kT = 32768;
constexpr int kThreads = 512;   // 8 waves, one block per row
}

__device__ inline void coeffs_f32(const float* g, const float* r,
                                  const float* mhp, const float* mbp,
                                  const float* mlp, float& b0, float& b1,
                                  float& b2, float& a1, float& a2) {
  float graw = g[0], rraw = r[0];
  float sig = 1.0f / (1.0f + expf(-graw));
  float gg = tanf(1.5707963267948966f * sig);            // tan(pi*sigmoid/2)
  float rr = (rraw > 20.0f) ? rraw : log1pf(expf(rraw)); // softplus
  float g2 = gg * gg;
  float m_hp = mhp[0], m_bp = mbp[0], m_lp = mlp[0];
  float B0 = g2 * m_lp + gg * m_bp + m_hp;
  float B1 = 2.0f * g2 * m_lp - 2.0f * m_hp;
  float B2 = g2 * m_lp - gg * m_bp + m_hp;
  float A0 = g2 + 2.0f * rr * gg + 1.0f;
  float A1 = 2.0f * g2 - 2.0f;
  float A2 = g2 - 2.0f * rr * gg + 1.0f;
  float inv = 1.0f / A0;
  b0 = B0 * inv; b1 = B1 * inv; b2 = B2 * inv;
  a1 = A1 * inv; a2 = A2 * inv;
}

#define IIR_STEP(xx, yy)                                         \
  do {                                                           \
    yy = fmaf(b0, xx, z1);                                       \
    z1 = fmaf(na1, yy, fmaf(b1, xx, z2));                        \
    z2 = fmaf(na2, yy, b2 * xx);                                 \
  } while (0)

#define MAT_SQ(w00, w01, w10, w11)                               \
  do {                                                           \
    double t00 = w00 * w00 + w01 * w10;                          \
    double t01 = w00 * w01 + w01 * w11;                          \
    double t10 = w10 * w00 + w11 * w10;                          \
    double t11 = w10 * w01 + w11 * w11;                          \
    w00 = t00; w01 = t01; w10 = t10; w11 = t11;                  \
  } while (0)

#define LGKM0() asm volatile("s_waitcnt lgkmcnt(0)" ::: "memory")

__device__ __forceinline__ int swz(int q) { return q ^ ((q >> 4) & 7); }

__global__ __launch_bounds__(kThreads) void k_fused(
    const float* __restrict__ x, const float* g, const float* r,
    const float* mhp, const float* mbp, const float* mlp,
    float* __restrict__ out) {
  // 4 KB used per wave; padded to 6 KB/wave so LDS total = 57,344 B ->
  // exactly 2 blocks/CU -> backend occupancy target 4 waves/EU (128 VGPR).
  __shared__ float4 tbuf[8][384];
  __shared__ double s1[kThreads], s2[kThreads];  // 8 KB scan buffer

  const int t = threadIdx.x;
  const int l = t & 63;            // lane
  const int wave = t >> 6;
  const size_t rowoff = (size_t)blockIdx.x * kT;

  float b0, b1, b2, a1, a2;
  coeffs_f32(g, r, mhp, mbp, mlp, b0, b1, b2, a1, a2);
  float na1 = -a1, na2 = -a2;

  const int dl = (l >> 2) & 3;     // local slice index when lane is active
  const int m16 = (l & 3) << 4;    // quad offset within slice
  const int actgrp = l >> 4;       // round in which this lane computes
  float4* wb = &tbuf[wave][0];
  const float4* xv = (const float4*)(x + rowoff) + (size_t)wave * 1024;

  // ---- stage-in + pass1 fused (pipelined): zero-init chunk state ----------
  float z1 = 0.f, z2 = 0.f;
  float4 v0 = xv[0 * 64 + l], v1 = xv[1 * 64 + l],
         v2 = xv[2 * 64 + l], v3 = xv[3 * 64 + l];
#pragma unroll
  for (int j = 0; j < 4; ++j) {
    float4 n0, n1, n2, n3;
    if (j < 3) {                   // issue next round's loads EARLY
      n0 = xv[(4 * (j + 1) + 0) * 64 + l];
      n1 = xv[(4 * (j + 1) + 1) * 64 + l];
      n2 = xv[(4 * (j + 1) + 2) * 64 + l];
      n3 = xv[(4 * (j + 1) + 3) * 64 + l];
    }
    if (j) LGKM0();                // prior round's LDS reads retired
    wb[swz(0 * 64 + l)] = v0;      // (compiler: vmcnt(4) — n stays in flight)
    wb[swz(1 * 64 + l)] = v1;
    wb[swz(2 * 64 + l)] = v2;
    wb[swz(3 * 64 + l)] = v3;
    LGKM0();                       // writes visible before cross-lane reads
    if (actgrp == j) {             // active lanes run their whole chunk now
#pragma unroll
      for (int k = 0; k < 16; ++k) {
        float4 q = wb[swz(dl * 64 + m16 + k)];
        float y;
        IIR_STEP(q.x, y); IIR_STEP(q.y, y);
        IIR_STEP(q.z, y); IIR_STEP(q.w, y);
      }
    }
    if (j < 3) { v0 = n0; v1 = n1; v2 = n2; v3 = n3; }
  }
  // every lane now holds d_t = (z1, z2): its chunk's zero-init final state

  // ---- pre-issue pass2 round-0 loads; scan barriers hide their latency ----
  float4 p0 = xv[0 * 64 + l], p1 = xv[1 * 64 + l],
         p2 = xv[2 * 64 + l], p3 = xv[3 * 64 + l];

  // ---- scan: f64 LDS Kogge-Stone over 512 chunks, P = M^64 ---------------
  double w00 = -(double)a1, w01 = 1.0, w10 = -(double)a2, w11 = 0.0;
#pragma unroll
  for (int i = 0; i < 6; ++i) MAT_SQ(w00, w01, w10, w11);  // P = M^64

  double A0 = (double)z1, A1 = (double)z2;
  for (int o = 1; o < kThreads; o <<= 1) {  // 9 steps
    s1[t] = A0; s2[t] = A1;
    __syncthreads();
    double q0 = 0.0, q1 = 0.0;
    if (t >= o) { q0 = s1[t - o]; q1 = s2[t - o]; }
    __syncthreads();
    A0 += w00 * q0 + w01 * q1;
    A1 += w10 * q0 + w11 * q1;
    MAT_SQ(w00, w01, w10, w11);
  }
  s1[t] = A0; s2[t] = A1;
  __syncthreads();
  double e0 = 0.0, e1 = 0.0;
  if (t > 0) { e0 = s1[t - 1]; e1 = s2[t - 1]; }  // entering state of chunk t

  // ---- pass2 (pipelined): rerun chunk from entering state, store y -------
  z1 = (float)e0; z2 = (float)e1;
  float4* yv = (float4*)(out + rowoff) + (size_t)wave * 1024;
#pragma unroll
  for (int j = 0; j < 4; ++j) {
    float4 n0, n1, n2, n3;
    if (j < 3) {                   // next round's x loads issued early
      n0 = xv[(4 * (j + 1) + 0) * 64 + l];
      n1 = xv[(4 * (j + 1) + 1) * 64 + l];
      n2 = xv[(4 * (j + 1) + 2) * 64 + l];
      n3 = xv[(4 * (j + 1) + 3) * 64 + l];
    }
    if (j) LGKM0();                // prior round's slice reads retired
    wb[swz(0 * 64 + l)] = p0;
    wb[swz(1 * 64 + l)] = p1;
    wb[swz(2 * 64 + l)] = p2;
    wb[swz(3 * 64 + l)] = p3;
    LGKM0();                       // x slices visible
    if (actgrp == j) {             // rerun chunk from true entering state
#pragma unroll
      for (int k = 0; k < 16; ++k) {
        int idx = swz(dl * 64 + m16 + k);
        float4 q = wb[idx];
        float4 o4;
        IIR_STEP(q.x, o4.x); IIR_STEP(q.y, o4.y);
        IIR_STEP(q.z, o4.z); IIR_STEP(q.w, o4.w);
        wb[idx] = o4;              // y back to the same slot
      }
    }
    LGKM0();                       // y writes visible before slice reads
    yv[(4 * j + 0) * 64 + l] = wb[swz(0 * 64 + l)];
    yv[(4 * j + 1) * 64 + l] = wb[swz(1 * 64 + l)];
    yv[(4 * j + 2) * 64 + l] = wb[swz(2 * 64 + l)];
    yv[(4 * j + 3) * 64 + l] = wb[swz(3 * 64 + l)];
    if (j < 3) { p0 = n0; p1 = n1; p2 = n2; p3 = n3; }
  }
}

extern "C" void kernel_launch(void* const* d_in, const int* in_sizes, int n_in,
                              void* d_out, int out_size, void* d_ws,
                              size_t ws_size, hipStream_t stream) {
  const float* x   = (const float*)d_in[0];
  const float* g   = (const float*)d_in[1];
  const float* r   = (const float*)d_in[2];
  const float* mhp = (const float*)d_in[3];
  const float* mbp = (const float*)d_in[4];
  const float* mlp = (const float*)d_in[5];
  float* out = (float*)d_out;
  (void)d_ws; (void)ws_size;

  k_fused<<<512, kThreads, 0, stream>>>(x, g, r, mhp, mbp, mlp, out);
}